// Round 1
// baseline (1995.416 us; speedup 1.0000x reference)
//
#include <hip/hip_runtime.h>
#include <hip/hip_bf16.h>
#include <math.h>

// Problem constants (B=1)
#define S_LEN 2048
#define H_NUM 16
#define D_DIM 64
#define E_DIM 1024
#define NC    127      // num compressed blocks: (S-32)/16 + 1
#define NSEL  32       // num selection blocks: S/64
#define TOPN  16
#define WIN   512
#define LSEL  64
#define SCALE 0.125f   // 1/sqrt(64)

__device__ __forceinline__ float wave_max(float v) {
#pragma unroll
    for (int off = 32; off; off >>= 1) v = fmaxf(v, __shfl_xor(v, off, 64));
    return v;
}
__device__ __forceinline__ float wave_sum(float v) {
#pragma unroll
    for (int off = 32; off; off >>= 1) v += __shfl_xor(v, off, 64);
    return v;
}

// dot of 64-float q (LDS) with 64-float k row (global), vectorized float4
__device__ __forceinline__ float dot64(const float* qs, const float* __restrict__ kr) {
    const float4* k4 = (const float4*)kr;
    const float4* q4 = (const float4*)qs;
    float acc = 0.f;
#pragma unroll
    for (int i = 0; i < 16; ++i) {
        float4 a = q4[i];
        float4 b = k4[i];
        acc = fmaf(a.x, b.x, fmaf(a.y, b.y, fmaf(a.z, b.z, fmaf(a.w, b.w, acc))));
    }
    return acc;
}

// ---- kernel 1: compressed (mean-pooled) K/V blocks: Kc/Vc [h][c][d] ----
__global__ __launch_bounds__(64) void nsa_compress(
    const float* __restrict__ k, const float* __restrict__ v,
    float* __restrict__ Kc, float* __restrict__ Vc)
{
    int bid = blockIdx.x;              // h*NC + c
    int h = bid / NC, c = bid % NC;
    int lane = threadIdx.x;            // = d
    int s0 = c * 16;
    float ak = 0.f, av = 0.f;
#pragma unroll 4
    for (int i = 0; i < 32; ++i) {
        int s = s0 + i;
        ak += k[((size_t)s * H_NUM + h) * D_DIM + lane];
        av += v[((size_t)s * H_NUM + h) * D_DIM + lane];
    }
    Kc[((size_t)h * NC + c) * D_DIM + lane] = ak * (1.f / 32.f);
    Vc[((size_t)h * NC + c) * D_DIM + lane] = av * (1.f / 32.f);
}

// ---- kernel 2: gating g = sigmoid(x @ Wg + bg), (S,3) ----
__global__ __launch_bounds__(64) void nsa_gate(
    const float* __restrict__ x, const float* __restrict__ Wg,
    const float* __restrict__ bg, float* __restrict__ g)
{
    int s = blockIdx.x, lane = threadIdx.x;
    float a0 = 0.f, a1 = 0.f, a2 = 0.f;
    for (int i = lane; i < E_DIM; i += 64) {
        float xv = x[(size_t)s * E_DIM + i];
        a0 = fmaf(xv, Wg[i * 3 + 0], a0);
        a1 = fmaf(xv, Wg[i * 3 + 1], a1);
        a2 = fmaf(xv, Wg[i * 3 + 2], a2);
    }
    a0 = wave_sum(a0); a1 = wave_sum(a1); a2 = wave_sum(a2);
    if (lane == 0) {
        g[s * 3 + 0] = 1.f / (1.f + expf(-(a0 + bg[0])));
        g[s * 3 + 1] = 1.f / (1.f + expf(-(a1 + bg[1])));
        g[s * 3 + 2] = 1.f / (1.f + expf(-(a2 + bg[2])));
    }
}

// ---- kernel 3: main NSA per (h, t) row. One wave per row. ----
__global__ __launch_bounds__(64) void nsa_main(
    const float* __restrict__ q, const float* __restrict__ k, const float* __restrict__ v,
    const float* __restrict__ Kc, const float* __restrict__ Vc,
    const float* __restrict__ g, float* __restrict__ out)
{
    const int bid = blockIdx.x;        // h*S + t (adjacent blocks share K/V tiles)
    const int h = bid >> 11;
    const int t = bid & (S_LEN - 1);
    const int lane = threadIdx.x;

    __shared__ __align__(16) float q_lds[D_DIM];
    __shared__ __align__(16) float p_lds[128];

    q_lds[lane] = q[((size_t)t * H_NUM + h) * D_DIM + lane];
    __syncthreads();

    // ================= branch 1: compressed attention =================
    // valid c: c*16+32 <= t+1  ->  nvalid = (t>=31) ? ((t-31)>>4)+1 : 0
    const int nvalid = (t >= 31) ? (((t - 31) >> 4) + 1) : 0;
    float s0 = -1e30f, s1 = -1e30f;
    if (lane < nvalid)
        s0 = SCALE * dot64(q_lds, Kc + ((size_t)h * NC + lane) * D_DIM);
    const int c2 = lane + 64;
    if (c2 < nvalid)
        s1 = SCALE * dot64(q_lds, Kc + ((size_t)h * NC + c2) * D_DIM);
    float m1 = wave_max(fmaxf(s0, s1));
    float e0 = (lane < nvalid) ? expf(s0 - m1) : 0.f;
    float e1 = (c2 < nvalid) ? expf(s1 - m1) : 0.f;
    float l1 = wave_sum(e0 + e1);
    float inv1 = (nvalid > 0) ? 1.f / l1 : 0.f;
    p_lds[lane] = e0 * inv1;
    p_lds[lane + 64] = e1 * inv1;
    __syncthreads();

    // o_cmp (lane = d)
    float oc = 0.f;
    for (int c = 0; c < nvalid; ++c)
        oc = fmaf(p_lds[c], Vc[((size_t)h * NC + c) * D_DIM + lane], oc);

    // p_sel: overlap of compressed block c=[16c,16c+32) with sel block n=[64n,64n+64)
    // -> c in [4n-1, 4n+3] clamped to [0, NC-1]
    float psel = 0.f;
    if (lane < NSEL) {
        int lo = 4 * lane - 1; if (lo < 0) lo = 0;
        int hi = 4 * lane + 3; if (hi > NC - 1) hi = NC - 1;
        for (int c = lo; c <= hi; ++c) psel += p_lds[c];
    }

    // top-16 with jax.lax.top_k tie semantics (stable: lowest index wins ties)
    unsigned selmask = 0u;
    for (int it = 0; it < TOPN; ++it) {
        float val = (lane < NSEL && !((selmask >> lane) & 1u)) ? psel : -1.f;
        int idx = lane;
#pragma unroll
        for (int off = 32; off; off >>= 1) {
            float ov = __shfl_xor(val, off, 64);
            int   oi = __shfl_xor(idx, off, 64);
            if (ov > val || (ov == val && oi < idx)) { val = ov; idx = oi; }
        }
        selmask |= (1u << idx);
    }
    selmask |= (1u << (t >> 6));   // always include own block

    // ================= branch 2: selected-block attention =================
    float m2 = -1e30f, l2 = 0.f, o2 = 0.f;
    for (int n = 0; n < NSEL; ++n) {
        int base = n << 6;
        if (base > t) break;                       // blocks ascend; rest have no valid tokens
        if (!((selmask >> n) & 1u)) continue;
        int j = base + lane;
        float sc = (j <= t) ? SCALE * dot64(q_lds, k + ((size_t)j * H_NUM + h) * D_DIM)
                            : -1e30f;
        float tm = wave_max(sc);
        float mnew = fmaxf(m2, tm);
        float alpha = expf(m2 - mnew);             // 0 on first tile (m2=-1e30)
        float p = (j <= t) ? expf(sc - mnew) : 0.f;
        __syncthreads();                           // previous tile's p_lds reads done
        p_lds[lane] = p;
        __syncthreads();
        l2 = l2 * alpha + wave_sum(p);
        float acc = 0.f;
        int lim = t - base + 1; if (lim > 64) lim = 64;
        for (int jj = 0; jj < lim; ++jj)
            acc = fmaf(p_lds[jj], v[((size_t)(base + jj) * H_NUM + h) * D_DIM + lane], acc);
        o2 = o2 * alpha + acc;
        m2 = mnew;
    }
    o2 /= l2;   // own block guarantees l2 > 0

    // ================= branch 3: sliding-window attention =================
    int wlo = t - (WIN - 1); if (wlo < 0) wlo = 0;
    float m3 = -1e30f, l3 = 0.f, o3 = 0.f;
    for (int base = (wlo >> 6) << 6; base <= t; base += 64) {
        int j = base + lane;
        bool ok = (j >= wlo) && (j <= t);
        float sc = ok ? SCALE * dot64(q_lds, k + ((size_t)j * H_NUM + h) * D_DIM)
                      : -1e30f;
        float tm = wave_max(sc);
        float mnew = fmaxf(m3, tm);
        float alpha = expf(m3 - mnew);
        float p = ok ? expf(sc - mnew) : 0.f;
        __syncthreads();
        p_lds[lane] = p;
        __syncthreads();
        l3 = l3 * alpha + wave_sum(p);
        float acc = 0.f;
        int j0 = (base > wlo) ? 0 : (wlo - base);
        int lim = t - base + 1; if (lim > 64) lim = 64;
        for (int jj = j0; jj < lim; ++jj)
            acc = fmaf(p_lds[jj], v[((size_t)(base + jj) * H_NUM + h) * D_DIM + lane], acc);
        o3 = o3 * alpha + acc;
        m3 = mnew;
    }
    o3 /= l3;   // token t itself guarantees l3 > 0

    // ================= gated combine =================
    float g0 = g[t * 3 + 0], g1 = g[t * 3 + 1], g2v = g[t * 3 + 2];
    out[((size_t)t * H_NUM + h) * D_DIM + lane] = g0 * oc + g1 * o2 + g2v * o3;
}

extern "C" void kernel_launch(void* const* d_in, const int* in_sizes, int n_in,
                              void* d_out, int out_size, void* d_ws, size_t ws_size,
                              hipStream_t stream) {
    const float* q  = (const float*)d_in[0];
    const float* k  = (const float*)d_in[1];
    const float* v  = (const float*)d_in[2];
    const float* x  = (const float*)d_in[3];
    const float* Wg = (const float*)d_in[4];
    const float* bg = (const float*)d_in[5];
    float* out = (float*)d_out;

    float* Kc = (float*)d_ws;                       // H*NC*D floats
    float* Vc = Kc + (size_t)H_NUM * NC * D_DIM;    // H*NC*D floats
    float* g  = Vc + (size_t)H_NUM * NC * D_DIM;    // S*3 floats

    nsa_compress<<<H_NUM * NC, 64, 0, stream>>>(k, v, Kc, Vc);
    nsa_gate<<<S_LEN, 64, 0, stream>>>(x, Wg, bg, g);
    nsa_main<<<S_LEN * H_NUM, 64, 0, stream>>>(q, k, v, Kc, Vc, g, out);
}

// Round 3
// 161.199 us; speedup vs baseline: 12.3786x; 12.3786x over previous
//
#include <hip/hip_runtime.h>
#include <hip/hip_bf16.h>
#include <math.h>

#define H_NUM 16
#define D_DIM 64
#define S_LEN 2048
#define E_DIM 1024
#define NC    127
#define TOPN  16
#define SCALE 0.125f

typedef short s16x8 __attribute__((ext_vector_type(8)));
typedef float f32x4 __attribute__((ext_vector_type(4)));

__device__ __forceinline__ unsigned short f2b(float f) {
    __hip_bfloat16 h = __float2bfloat16(f);
    return *reinterpret_cast<unsigned short*>(&h);
}
__device__ __forceinline__ float b2f(unsigned short u) {
    __hip_bfloat16 h = *reinterpret_cast<__hip_bfloat16*>(&u);
    return __bfloat162float(h);
}
__device__ __forceinline__ s16x8 pack8(float4 a, float4 b) {
    s16x8 r;
    r[0] = (short)f2b(a.x); r[1] = (short)f2b(a.y);
    r[2] = (short)f2b(a.z); r[3] = (short)f2b(a.w);
    r[4] = (short)f2b(b.x); r[5] = (short)f2b(b.y);
    r[6] = (short)f2b(b.z); r[7] = (short)f2b(b.w);
    return r;
}
__device__ __forceinline__ f32x4 mfma16(s16x8 a, s16x8 b, f32x4 c) {
    return __builtin_amdgcn_mfma_f32_16x16x32_bf16(a, b, c, 0, 0, 0);
}
// swizzled LDS index helpers (units: ushort for sw64/sw128, float for swP)
__device__ __forceinline__ int sw64(int r, int c)  { return r * 64  + (c ^ ((r & 7) << 3)); }
__device__ __forceinline__ int sw128(int r, int c) { return r * 128 + (c ^ ((r & 7) << 3)); }
__device__ __forceinline__ int swP(int r, int c)   { return r * 128 + (c ^ ((r & 7) << 2)); }

__device__ __forceinline__ float wave_sum(float v) {
#pragma unroll
    for (int off = 32; off; off >>= 1) v += __shfl_xor(v, off, 64);
    return v;
}

// ---- kernel 1: compressed (mean-pooled) K/V blocks: Kc/Vc [h][c][d] f32 ----
__global__ __launch_bounds__(64) void nsa_compress(
    const float* __restrict__ k, const float* __restrict__ v,
    float* __restrict__ Kc, float* __restrict__ Vc)
{
    int bid = blockIdx.x;              // h*NC + c
    int h = bid / NC, c = bid % NC;
    int lane = threadIdx.x;            // = d
    int s0 = c * 16;
    float ak = 0.f, av = 0.f;
#pragma unroll 4
    for (int i = 0; i < 32; ++i) {
        int s = s0 + i;
        ak += k[((size_t)s * H_NUM + h) * D_DIM + lane];
        av += v[((size_t)s * H_NUM + h) * D_DIM + lane];
    }
    Kc[((size_t)h * NC + c) * D_DIM + lane] = ak * (1.f / 32.f);
    Vc[((size_t)h * NC + c) * D_DIM + lane] = av * (1.f / 32.f);
}

// ---- kernel 2: gating g = sigmoid(x @ Wg + bg), (S,3) ----
__global__ __launch_bounds__(64) void nsa_gate(
    const float* __restrict__ x, const float* __restrict__ Wg,
    const float* __restrict__ bg, float* __restrict__ g)
{
    int s = blockIdx.x, lane = threadIdx.x;
    float a0 = 0.f, a1 = 0.f, a2 = 0.f;
    for (int i = lane; i < E_DIM; i += 64) {
        float xv = x[(size_t)s * E_DIM + i];
        a0 = fmaf(xv, Wg[i * 3 + 0], a0);
        a1 = fmaf(xv, Wg[i * 3 + 1], a1);
        a2 = fmaf(xv, Wg[i * 3 + 2], a2);
    }
    a0 = wave_sum(a0); a1 = wave_sum(a1); a2 = wave_sum(a2);
    if (lane == 0) {
        g[s * 3 + 0] = 1.f / (1.f + expf(-(a0 + bg[0])));
        g[s * 3 + 1] = 1.f / (1.f + expf(-(a1 + bg[1])));
        g[s * 3 + 2] = 1.f / (1.f + expf(-(a2 + bg[2])));
    }
}

// ---- kernel 3: main NSA. One block = (head h, 64-query tile). 4 waves. ----
// LDS overlay (80 KB total -> 2 blocks/CU):
//   [0,16K)   KA  ushort: phase1 Kc-hi [128][64]; phase2 K-tile [64][64]
//   [16K,32K) VB  ushort: phase1 VcT [64][128];   phase2 VT-tile [64][64]
//   [32K,64K) Pl  f32 [4 waves][16][128]
//   [64K,80K) KL  ushort Kc-lo [128][64] (dead after branch-1 QK)
//             aliased by: psl f32 [64][33] (+8448B) then selm u32[64]
__global__ __launch_bounds__(256) void nsa_main(
    const float* __restrict__ q, const float* __restrict__ k, const float* __restrict__ v,
    const float* __restrict__ Kc, const float* __restrict__ Vc,
    const float* __restrict__ gat, float* __restrict__ out)
{
    __shared__ __align__(16) char smem[81920];
    unsigned short* KA  = (unsigned short*)(smem);
    unsigned short* VB  = (unsigned short*)(smem + 16384);
    float*          Pl  = (float*)(smem + 32768);
    unsigned short* KL  = (unsigned short*)(smem + 65536);
    float*          psl = (float*)(smem + 65536);
    unsigned int*  selm = (unsigned int*)(smem + 65536 + 8448);

    const int bid  = blockIdx.x;
    const int h    = bid & 15;
    const int grp  = bid >> 4;
    const int tile = (grp < 16) ? (31 - grp) : (grp - 16);  // pair big tiles with small on a CU
    const int t0   = tile << 6;
    const int tid  = threadIdx.x;
    const int w    = tid >> 6;
    const int lane = tid & 63;
    const int lr   = lane & 15;
    const int g    = lane >> 4;

    float* Pw = Pl + w * (16 * 128);

    int trow[4];
#pragma unroll
    for (int r = 0; r < 4; ++r) trow[r] = t0 + 16 * w + 4 * g + r;

    // ---- Q A-frags, split hi/lo (hi+lo ~ fp32 for branch-1 selection fidelity) ----
    s16x8 qa[2], ql[2];
    {
        const float* qrow = q + ((size_t)(t0 + 16 * w + lr) * H_NUM + h) * D_DIM;
#pragma unroll
        for (int kk = 0; kk < 2; ++kk) {
            float4 a = *(const float4*)(qrow + kk * 32 + g * 8);
            float4 b = *(const float4*)(qrow + kk * 32 + g * 8 + 4);
            s16x8 hi = pack8(a, b);
            float4 ar, br;
            ar.x = a.x - b2f((unsigned short)hi[0]); ar.y = a.y - b2f((unsigned short)hi[1]);
            ar.z = a.z - b2f((unsigned short)hi[2]); ar.w = a.w - b2f((unsigned short)hi[3]);
            br.x = b.x - b2f((unsigned short)hi[4]); br.y = b.y - b2f((unsigned short)hi[5]);
            br.z = b.z - b2f((unsigned short)hi[6]); br.w = b.w - b2f((unsigned short)hi[7]);
            qa[kk] = hi;
            ql[kk] = pack8(ar, br);
        }
    }

    // ---- stage Kc -> KA(hi)/KL(lo) [128][64], Vc^T -> VB [64][128] ----
    for (int idx = tid; idx < 128 * 16; idx += 256) {
        int c = idx >> 4, d0 = (idx & 15) << 2;
        float4 kc4 = {0.f, 0.f, 0.f, 0.f}, vc4 = {0.f, 0.f, 0.f, 0.f};
        if (c < NC) {
            kc4 = *(const float4*)(Kc + ((size_t)h * NC + c) * D_DIM + d0);
            vc4 = *(const float4*)(Vc + ((size_t)h * NC + c) * D_DIM + d0);
        }
        unsigned short* ka = &KA[sw64(c, d0)];
        unsigned short* kl = &KL[sw64(c, d0)];
        float cf[4] = {kc4.x, kc4.y, kc4.z, kc4.w};
#pragma unroll
        for (int j = 0; j < 4; ++j) {
            unsigned short hi = f2b(cf[j]);
            ka[j] = hi;
            kl[j] = f2b(cf[j] - b2f(hi));
        }
        VB[sw128(d0 + 0, c)] = f2b(vc4.x);
        VB[sw128(d0 + 1, c)] = f2b(vc4.y);
        VB[sw128(d0 + 2, c)] = f2b(vc4.z);
        VB[sw128(d0 + 3, c)] = f2b(vc4.w);
    }
    __syncthreads();

    // ================= branch 1: S_c = Q · Kc^T, split precision =================
    f32x4 sc8[8];
#pragma unroll
    for (int ct = 0; ct < 8; ++ct) {
        f32x4 acc = {0.f, 0.f, 0.f, 0.f};
#pragma unroll
        for (int kk = 0; kk < 2; ++kk) {
            s16x8 khi = *(const s16x8*)&KA[sw64(16 * ct + lr, kk * 32 + g * 8)];
            s16x8 klo = *(const s16x8*)&KL[sw64(16 * ct + lr, kk * 32 + g * 8)];
            acc = mfma16(qa[kk], khi, acc);
            acc = mfma16(ql[kk], khi, acc);
            acc = mfma16(qa[kk], klo, acc);
        }
        sc8[ct] = acc;
    }

    int nv[4];
#pragma unroll
    for (int r = 0; r < 4; ++r) nv[r] = (trow[r] >= 31) ? (((trow[r] - 31) >> 4) + 1) : 0;

    float pm[4] = {-3e38f, -3e38f, -3e38f, -3e38f};
#pragma unroll
    for (int ct = 0; ct < 8; ++ct)
#pragma unroll
        for (int r = 0; r < 4; ++r) {
            int c = 16 * ct + lr;
            float s = sc8[ct][r] * SCALE;
            if (c < nv[r]) pm[r] = fmaxf(pm[r], s);
        }
#pragma unroll
    for (int off = 8; off >= 1; off >>= 1)
#pragma unroll
        for (int r = 0; r < 4; ++r) pm[r] = fmaxf(pm[r], __shfl_xor(pm[r], off, 64));

    float l1[4] = {0.f, 0.f, 0.f, 0.f};
#pragma unroll
    for (int ct = 0; ct < 8; ++ct)
#pragma unroll
        for (int r = 0; r < 4; ++r) {
            int c = 16 * ct + lr;
            float p = (c < nv[r]) ? __expf(sc8[ct][r] * SCALE - pm[r]) : 0.f;
            l1[r] += p;
            Pw[swP(4 * g + r, 16 * ct + lr)] = p;   // unnormalized (ranking & PV scale out)
        }
#pragma unroll
    for (int off = 8; off >= 1; off >>= 1)
#pragma unroll
        for (int r = 0; r < 4; ++r) l1[r] += __shfl_xor(l1[r], off, 64);
    __syncthreads();   // Pw visible; KL dead from here (psl aliases it)

    // ---- psel: overlap-sum of P over compressed blocks c in [4n-1, 4n+3] ----
    for (int p = tid; p < 64 * 32; p += 256) {
        int row = p >> 5, n = p & 31;
        int lo = 4 * n - 1; if (lo < 0) lo = 0;
        int hi = 4 * n + 3; if (hi > NC - 1) hi = NC - 1;
        const float* Pr = Pl + (row >> 4) * (16 * 128);
        int rr = row & 15;
        float s = 0.f;
        for (int c = lo; c <= hi; ++c) s += Pr[swP(rr, c)];
        psl[row * 33 + n] = s;
    }
    __syncthreads();

    // ---- top-16 per row (jax tie semantics: ascending scan, strict >) ----
    if (tid < 64) {
        unsigned m = 0u;
        for (int it = 0; it < TOPN; ++it) {
            float best = -1.f; int bi = 0;
            for (int n = 0; n < 32; ++n) {
                if ((m >> n) & 1u) continue;
                float val = psl[tid * 33 + n];
                if (val > best) { best = val; bi = n; }
            }
            m |= 1u << bi;
        }
        selm[tid] = m | (1u << tile);   // always include own block
    }

    // ---- o_cmp = P · Vc (unnormalized; scaled by 1/l1 in epilogue) ----
    f32x4 oc[4];
#pragma unroll
    for (int dt = 0; dt < 4; ++dt) { f32x4 z = {0.f, 0.f, 0.f, 0.f}; oc[dt] = z; }
#pragma unroll
    for (int kk = 0; kk < 4; ++kk) {
        float4 a0 = *(const float4*)&Pw[swP(lr, kk * 32 + g * 8)];
        float4 a1 = *(const float4*)&Pw[swP(lr, kk * 32 + g * 8 + 4)];
        s16x8 pa = pack8(a0, a1);
#pragma unroll
        for (int dt = 0; dt < 4; ++dt)
            oc[dt] = mfma16(pa, *(const s16x8*)&VB[sw128(16 * dt + lr, kk * 32 + g * 8)], oc[dt]);
    }
    __syncthreads();

    // ---- per-row masks + block-uniform union ----
    unsigned selreg[4];
#pragma unroll
    for (int r = 0; r < 4; ++r) selreg[r] = selm[16 * w + 4 * g + r];
    unsigned um = selm[lane];
#pragma unroll
    for (int off = 32; off >= 1; off >>= 1) um |= __shfl_xor(um, off, 64);

    // window needs blocks down to floor((t0-511)/64) = tile-8
    const int winlo = (tile >= 8) ? (tile - 8) : 0;

    float m2[4], l2[4], m3[4], l3[4];
    f32x4 o2[4], o3[4];
#pragma unroll
    for (int r = 0; r < 4; ++r) { m2[r] = -1e30f; l2[r] = 0.f; m3[r] = -1e30f; l3[r] = 0.f; }
#pragma unroll
    for (int dt = 0; dt < 4; ++dt) { f32x4 z = {0.f, 0.f, 0.f, 0.f}; o2[dt] = z; o3[dt] = z; }

    // ================= branches 2+3: shared QK^T per K-tile =================
    for (int n = 0; n <= tile; ++n) {
        const bool sel_on = (um >> n) & 1u;
        const bool win_on = n >= winlo;
        if (!sel_on && !win_on) continue;
        const int base = n << 6;

        // stage K tile [tok][d] and V^T tile [d][tok]
        for (int idx = tid; idx < 64 * 16; idx += 256) {
            int tok = idx >> 4, d0 = (idx & 15) << 2;
            float4 kv = *(const float4*)(k + ((size_t)(base + tok) * H_NUM + h) * D_DIM + d0);
            float4 vv = *(const float4*)(v + ((size_t)(base + tok) * H_NUM + h) * D_DIM + d0);
            unsigned short* ka = &KA[sw64(tok, d0)];
            ka[0] = f2b(kv.x); ka[1] = f2b(kv.y); ka[2] = f2b(kv.z); ka[3] = f2b(kv.w);
            VB[sw64(d0 + 0, tok)] = f2b(vv.x);
            VB[sw64(d0 + 1, tok)] = f2b(vv.y);
            VB[sw64(d0 + 2, tok)] = f2b(vv.z);
            VB[sw64(d0 + 3, tok)] = f2b(vv.w);
        }
        __syncthreads();

        f32x4 s4[4];
#pragma unroll
        for (int ct = 0; ct < 4; ++ct) {
            f32x4 acc = {0.f, 0.f, 0.f, 0.f};
#pragma unroll
            for (int kk = 0; kk < 2; ++kk)
                acc = mfma16(qa[kk], *(const s16x8*)&KA[sw64(16 * ct + lr, kk * 32 + g * 8)], acc);
            s4[ct] = acc;
        }

        if (sel_on) {
            float rm[4] = {-3e38f, -3e38f, -3e38f, -3e38f};
#pragma unroll
            for (int ct = 0; ct < 4; ++ct)
#pragma unroll
                for (int r = 0; r < 4; ++r) {
                    int j = base + 16 * ct + lr;
                    bool ok = ((selreg[r] >> n) & 1u) && (j <= trow[r]);
                    float s = s4[ct][r] * SCALE;
                    if (ok) rm[r] = fmaxf(rm[r], s);
                }
#pragma unroll
            for (int off = 8; off >= 1; off >>= 1)
#pragma unroll
                for (int r = 0; r < 4; ++r) rm[r] = fmaxf(rm[r], __shfl_xor(rm[r], off, 64));
            float al[4], rs[4] = {0.f, 0.f, 0.f, 0.f};
#pragma unroll
            for (int r = 0; r < 4; ++r) {
                float mn = fmaxf(m2[r], rm[r]);
                al[r] = __expf(m2[r] - mn);
                m2[r] = mn;
            }
#pragma unroll
            for (int ct = 0; ct < 4; ++ct)
#pragma unroll
                for (int r = 0; r < 4; ++r) {
                    int j = base + 16 * ct + lr;
                    bool ok = ((selreg[r] >> n) & 1u) && (j <= trow[r]);
                    float p = ok ? __expf(s4[ct][r] * SCALE - m2[r]) : 0.f;
                    rs[r] += p;
                    Pw[swP(4 * g + r, 16 * ct + lr)] = p;
                }
#pragma unroll
            for (int off = 8; off >= 1; off >>= 1)
#pragma unroll
                for (int r = 0; r < 4; ++r) rs[r] += __shfl_xor(rs[r], off, 64);
#pragma unroll
            for (int r = 0; r < 4; ++r) l2[r] = l2[r] * al[r] + rs[r];
#pragma unroll
            for (int dt = 0; dt < 4; ++dt)
#pragma unroll
                for (int r = 0; r < 4; ++r) o2[dt][r] *= al[r];
        }
        if (win_on) {
            float rm[4] = {-3e38f, -3e38f, -3e38f, -3e38f};
#pragma unroll
            for (int ct = 0; ct < 4; ++ct)
#pragma unroll
                for (int r = 0; r < 4; ++r) {
                    int j = base + 16 * ct + lr;
                    bool ok = (j >= trow[r] - 511) && (j <= trow[r]);
                    float s = s4[ct][r] * SCALE;
                    if (ok) rm[r] = fmaxf(rm[r], s);
                }
#pragma unroll
            for (int off = 8; off >= 1; off >>= 1)
#pragma unroll
                for (int r = 0; r < 4; ++r) rm[r] = fmaxf(rm[r], __shfl_xor(rm[r], off, 64));
            float al[4], rs[4] = {0.f, 0.f, 0.f, 0.f};
#pragma unroll
            for (int r = 0; r < 4; ++r) {
                float mn = fmaxf(m3[r], rm[r]);
                al[r] = __expf(m3[r] - mn);
                m3[r] = mn;
            }
#pragma unroll
            for (int ct = 0; ct < 4; ++ct)
#pragma unroll
                for (int r = 0; r < 4; ++r) {
                    int j = base + 16 * ct + lr;
                    bool ok = (j >= trow[r] - 511) && (j <= trow[r]);
                    float p = ok ? __expf(s4[ct][r] * SCALE - m3[r]) : 0.f;
                    rs[r] += p;
                    Pw[swP(4 * g + r, 64 + 16 * ct + lr)] = p;
                }
#pragma unroll
            for (int off = 8; off >= 1; off >>= 1)
#pragma unroll
                for (int r = 0; r < 4; ++r) rs[r] += __shfl_xor(rs[r], off, 64);
#pragma unroll
            for (int r = 0; r < 4; ++r) l3[r] = l3[r] * al[r] + rs[r];
#pragma unroll
            for (int dt = 0; dt < 4; ++dt)
#pragma unroll
                for (int r = 0; r < 4; ++r) o3[dt][r] *= al[r];
        }
        __syncthreads();   // P writes (cross-lane) -> P reads

        if (sel_on) {
#pragma unroll
            for (int kk = 0; kk < 2; ++kk) {
                float4 a0 = *(const float4*)&Pw[swP(lr, kk * 32 + g * 8)];
                float4 a1 = *(const float4*)&Pw[swP(lr, kk * 32 + g * 8 + 4)];
                s16x8 pa = pack8(a0, a1);
#pragma unroll
                for (int dt = 0; dt < 4; ++dt)
                    o2[dt] = mfma16(pa, *(const s16x8*)&VB[sw64(16 * dt + lr, kk * 32 + g * 8)], o2[dt]);
            }
        }
        if (win_on) {
#pragma unroll
            for (int kk = 0; kk < 2; ++kk) {
                float4 a0 = *(const float4*)&Pw[swP(lr, 64 + kk * 32 + g * 8)];
                float4 a1 = *(const float4*)&Pw[swP(lr, 64 + kk * 32 + g * 8 + 4)];
                s16x8 pa = pack8(a0, a1);
#pragma unroll
                for (int dt = 0; dt < 4; ++dt)
                    o3[dt] = mfma16(pa, *(const s16x8*)&VB[sw64(16 * dt + lr, kk * 32 + g * 8)], o3[dt]);
            }
        }
        __syncthreads();   // before next tile overwrites KA/VB
    }

    // ================= gated combine =================
#pragma unroll
    for (int r = 0; r < 4; ++r) {
        const float* gp = gat + (size_t)trow[r] * 3;
        float g0 = gp[0], g1 = gp[1], g2 = gp[2];
        float invc = nv[r] ? (1.f / l1[r]) : 0.f;
        float i2 = 1.f / l2[r], i3 = 1.f / l3[r];
#pragma unroll
        for (int dt = 0; dt < 4; ++dt) {
            float val = g0 * (oc[dt][r] * invc) + g1 * (o2[dt][r] * i2) + g2 * (o3[dt][r] * i3);
            out[((size_t)trow[r] * H_NUM + h) * D_DIM + 16 * dt + lr] = val;
        }
    }
}

extern "C" void kernel_launch(void* const* d_in, const int* in_sizes, int n_in,
                              void* d_out, int out_size, void* d_ws, size_t ws_size,
                              hipStream_t stream) {
    const float* q  = (const float*)d_in[0];
    const float* k  = (const float*)d_in[1];
    const float* v  = (const float*)d_in[2];
    const float* x  = (const float*)d_in[3];
    const float* Wg = (const float*)d_in[4];
    const float* bg = (const float*)d_in[5];
    float* out = (float*)d_out;

    float* Kc = (float*)d_ws;                       // H*NC*D floats
    float* Vc = Kc + (size_t)H_NUM * NC * D_DIM;    // H*NC*D floats
    float* g  = Vc + (size_t)H_NUM * NC * D_DIM;    // S*3 floats

    nsa_compress<<<H_NUM * NC, 64, 0, stream>>>(k, v, Kc, Vc);
    nsa_gate<<<S_LEN, 64, 0, stream>>>(x, Wg, bg, g);
    nsa_main<<<512, 256, 0, stream>>>(q, k, v, Kc, Vc, g, out);
}

// Round 4
// 152.320 us; speedup vs baseline: 13.1002x; 1.0583x over previous
//
#include <hip/hip_runtime.h>
#include <hip/hip_bf16.h>
#include <math.h>

#define H_NUM 16
#define D_DIM 64
#define S_LEN 2048
#define E_DIM 1024
#define NC    127
#define TOPN  16
#define SCALE 0.125f

typedef short s16x8 __attribute__((ext_vector_type(8)));
typedef short s16x4 __attribute__((ext_vector_type(4)));
typedef float f32x4 __attribute__((ext_vector_type(4)));
typedef unsigned short ushort_t;

__device__ __forceinline__ unsigned short f2b(float f) {
    __hip_bfloat16 h = __float2bfloat16(f);
    return *reinterpret_cast<unsigned short*>(&h);
}
__device__ __forceinline__ float b2f(unsigned short u) {
    __hip_bfloat16 h = *reinterpret_cast<__hip_bfloat16*>(&u);
    return __bfloat162float(h);
}
__device__ __forceinline__ s16x8 pack8(float4 a, float4 b) {
    s16x8 r;
    r[0] = (short)f2b(a.x); r[1] = (short)f2b(a.y);
    r[2] = (short)f2b(a.z); r[3] = (short)f2b(a.w);
    r[4] = (short)f2b(b.x); r[5] = (short)f2b(b.y);
    r[6] = (short)f2b(b.z); r[7] = (short)f2b(b.w);
    return r;
}
__device__ __forceinline__ f32x4 mfma16(s16x8 a, s16x8 b, f32x4 c) {
    return __builtin_amdgcn_mfma_f32_16x16x32_bf16(a, b, c, 0, 0, 0);
}
// in-wave LDS write->read fence (DS ops of one wave complete in order;
// waitcnt drains, sched_barrier stops compiler motion across it — rule 18)
__device__ __forceinline__ void wave_lds_fence() {
    asm volatile("s_waitcnt lgkmcnt(0)" ::: "memory");
    __builtin_amdgcn_sched_barrier(0);
}
// swizzled index helpers: f32 [16][128] and ushort [16][128]
__device__ __forceinline__ int swP(int r, int c) { return r * 128 + (c ^ ((r & 7) << 2)); }
__device__ __forceinline__ int swB(int r, int c) { return r * 128 + (c ^ ((r & 7) << 3)); }

__device__ __forceinline__ float wave_sum(float v) {
#pragma unroll
    for (int off = 32; off; off >>= 1) v += __shfl_xor(v, off, 64);
    return v;
}

// ---- prep 1: compressed blocks -> KcHi/KcLo bf16 [h][128][64], VcT bf16 [h][64][128] ----
__global__ __launch_bounds__(64) void nsa_compress(
    const float* __restrict__ k, const float* __restrict__ v,
    ushort_t* __restrict__ KcHi, ushort_t* __restrict__ KcLo, ushort_t* __restrict__ VcT)
{
    int bid = blockIdx.x;              // h*128 + c  (c=127 is zero pad)
    int h = bid >> 7, c = bid & 127;
    int lane = threadIdx.x;            // = d
    float mk = 0.f, mv = 0.f;
    if (c < NC) {
        int s0 = c * 16;
#pragma unroll 4
        for (int i = 0; i < 32; ++i) {
            mk += k[((size_t)(s0 + i) * H_NUM + h) * D_DIM + lane];
            mv += v[((size_t)(s0 + i) * H_NUM + h) * D_DIM + lane];
        }
        mk *= (1.f / 32.f); mv *= (1.f / 32.f);
    }
    unsigned short khi = f2b(mk);
    KcHi[((size_t)h * 128 + c) * 64 + lane] = khi;
    KcLo[((size_t)h * 128 + c) * 64 + lane] = f2b(mk - b2f(khi));
    VcT[((size_t)h * 64 + lane) * 128 + c] = f2b(mv);
}

// ---- prep 2: K f32 [s][h][d] -> Kb bf16 [h][s][d] ----
__global__ __launch_bounds__(256) void nsa_cast_k(
    const float* __restrict__ k, ushort_t* __restrict__ Kb)
{
    int idx = (blockIdx.x * 256 + threadIdx.x) * 4;   // linear in Kb, 2M elements
    int d = idx & 63, s = (idx >> 6) & 2047, h = idx >> 17;
    float4 f = *(const float4*)(k + ((size_t)s * H_NUM + h) * D_DIM + d);
    s16x4 u;
    u[0] = (short)f2b(f.x); u[1] = (short)f2b(f.y);
    u[2] = (short)f2b(f.z); u[3] = (short)f2b(f.w);
    *(s16x4*)(Kb + idx) = u;
}

// ---- prep 3: V f32 [s][h][d] -> VtB bf16 [h][d][s] (LDS transpose per 128-token chunk) ----
__global__ __launch_bounds__(256) void nsa_cast_vt(
    const float* __restrict__ v, ushort_t* __restrict__ VtB)
{
    __shared__ ushort_t T[64][136];
    int h = blockIdx.x >> 4, s0 = (blockIdx.x & 15) << 7;
    int tid = threadIdx.x;
#pragma unroll
    for (int rep = 0; rep < 8; ++rep) {
        int idx = rep * 256 + tid;           // 0..2047 float4-groups
        int i = idx >> 4, d4 = (idx & 15) << 2;
        float4 f = *(const float4*)(v + ((size_t)(s0 + i) * H_NUM + h) * D_DIM + d4);
        T[d4 + 0][i] = f2b(f.x); T[d4 + 1][i] = f2b(f.y);
        T[d4 + 2][i] = f2b(f.z); T[d4 + 3][i] = f2b(f.w);
    }
    __syncthreads();
    int d = tid >> 2, i0 = (tid & 3) << 5;
    ushort_t* dst = VtB + ((size_t)h * 64 + d) * 2048 + s0 + i0;
#pragma unroll
    for (int jj = 0; jj < 32; jj += 8)
        *(s16x8*)(dst + jj) = *(const s16x8*)&T[d][i0 + jj];
}

// ---- prep 4: gating g = sigmoid(x @ Wg + bg), (S,3) ----
__global__ __launch_bounds__(64) void nsa_gate(
    const float* __restrict__ x, const float* __restrict__ Wg,
    const float* __restrict__ bg, float* __restrict__ g)
{
    int s = blockIdx.x, lane = threadIdx.x;
    float a0 = 0.f, a1 = 0.f, a2 = 0.f;
    for (int i = lane; i < E_DIM; i += 64) {
        float xv = x[(size_t)s * E_DIM + i];
        a0 = fmaf(xv, Wg[i * 3 + 0], a0);
        a1 = fmaf(xv, Wg[i * 3 + 1], a1);
        a2 = fmaf(xv, Wg[i * 3 + 2], a2);
    }
    a0 = wave_sum(a0); a1 = wave_sum(a1); a2 = wave_sum(a2);
    if (lane == 0) {
        g[s * 3 + 0] = 1.f / (1.f + expf(-(a0 + bg[0])));
        g[s * 3 + 1] = 1.f / (1.f + expf(-(a1 + bg[1])));
        g[s * 3 + 2] = 1.f / (1.f + expf(-(a2 + bg[2])));
    }
}

// ---- main: one block = (head, 64-query tile), 4 independent waves (16 rows each).
// No __syncthreads. K/V MFMA B-frags loaded directly from global bf16 (L1/L2).
// LDS 40KB: per-wave P buffer (f32 [16][128], reused as bf16 sel+win in phase 2)
// + per-wave psel [32][16]. -> 4 blocks/CU.
__global__ __launch_bounds__(256) void nsa_main(
    const float* __restrict__ q,
    const ushort_t* __restrict__ Kb, const ushort_t* __restrict__ VtB,
    const ushort_t* __restrict__ KcHi, const ushort_t* __restrict__ KcLo,
    const ushort_t* __restrict__ VcT,
    const float* __restrict__ gat, float* __restrict__ out)
{
    __shared__ __align__(16) float Pl[4 * 2048];   // per-wave 8KB
    __shared__ __align__(16) float psl[4 * 512];   // per-wave [32][16]

    const int bid  = blockIdx.x;
    const int h    = bid & 15;
    const int grp  = bid >> 4;
    const int tile = (grp < 16) ? (31 - grp) : (grp - 16);  // big tiles dispatch first
    const int t0   = tile << 6;
    const int tid  = threadIdx.x;
    const int w    = tid >> 6;
    const int lane = tid & 63;
    const int lr   = lane & 15;
    const int g    = lane >> 4;

    float*    Pw   = Pl + w * 2048;
    ushort_t* Pb   = (ushort_t*)Pw;       // phase 2: sel at [0,2048), win at [2048,4096) ushorts
    float*    pslw = psl + w * 512;

    int trow[4];
#pragma unroll
    for (int r = 0; r < 4; ++r) trow[r] = t0 + 16 * w + 4 * g + r;

    // ---- Q A-frags, split hi/lo ----
    s16x8 qa[2], ql[2];
    {
        const float* qrow = q + ((size_t)(t0 + 16 * w + lr) * H_NUM + h) * D_DIM;
#pragma unroll
        for (int kk = 0; kk < 2; ++kk) {
            float4 a = *(const float4*)(qrow + kk * 32 + g * 8);
            float4 b = *(const float4*)(qrow + kk * 32 + g * 8 + 4);
            s16x8 hi = pack8(a, b);
            float4 ar, br;
            ar.x = a.x - b2f((unsigned short)hi[0]); ar.y = a.y - b2f((unsigned short)hi[1]);
            ar.z = a.z - b2f((unsigned short)hi[2]); ar.w = a.w - b2f((unsigned short)hi[3]);
            br.x = b.x - b2f((unsigned short)hi[4]); br.y = b.y - b2f((unsigned short)hi[5]);
            br.z = b.z - b2f((unsigned short)hi[6]); br.w = b.w - b2f((unsigned short)hi[7]);
            qa[kk] = hi;
            ql[kk] = pack8(ar, br);
        }
    }

    // ================= branch 1: S_c = Q · Kc^T (split precision, B from global) =================
    f32x4 sc8[8];
#pragma unroll
    for (int ct = 0; ct < 8; ++ct) {
        f32x4 acc = {0.f, 0.f, 0.f, 0.f};
#pragma unroll
        for (int kk = 0; kk < 2; ++kk) {
            const size_t off = ((size_t)h * 128 + 16 * ct + lr) * 64 + kk * 32 + g * 8;
            s16x8 khi = *(const s16x8*)(KcHi + off);
            s16x8 klo = *(const s16x8*)(KcLo + off);
            acc = mfma16(qa[kk], khi, acc);
            acc = mfma16(ql[kk], khi, acc);
            acc = mfma16(qa[kk], klo, acc);
        }
        sc8[ct] = acc;
    }

    int nv[4];
#pragma unroll
    for (int r = 0; r < 4; ++r) nv[r] = (trow[r] >= 31) ? (((trow[r] - 31) >> 4) + 1) : 0;

    float pm[4] = {-3e38f, -3e38f, -3e38f, -3e38f};
#pragma unroll
    for (int ct = 0; ct < 8; ++ct)
#pragma unroll
        for (int r = 0; r < 4; ++r) {
            int c = 16 * ct + lr;
            float s = sc8[ct][r] * SCALE;
            if (c < nv[r]) pm[r] = fmaxf(pm[r], s);
        }
#pragma unroll
    for (int off = 8; off >= 1; off >>= 1)
#pragma unroll
        for (int r = 0; r < 4; ++r) pm[r] = fmaxf(pm[r], __shfl_xor(pm[r], off, 64));

    float l1[4] = {0.f, 0.f, 0.f, 0.f};
#pragma unroll
    for (int ct = 0; ct < 8; ++ct)
#pragma unroll
        for (int r = 0; r < 4; ++r) {
            int c = 16 * ct + lr;
            float p = (c < nv[r]) ? __expf(sc8[ct][r] * SCALE - pm[r]) : 0.f;
            l1[r] += p;
            Pw[swP(4 * g + r, 16 * ct + lr)] = p;   // unnormalized
        }
#pragma unroll
    for (int off = 8; off >= 1; off >>= 1)
#pragma unroll
        for (int r = 0; r < 4; ++r) l1[r] += __shfl_xor(l1[r], off, 64);
    wave_lds_fence();

    // ---- psel (per wave, its 16 rows): sum P over c in [4n-1, 4n+3]; pslw[n][row] ----
#pragma unroll
    for (int rep = 0; rep < 8; ++rep) {
        int item = rep * 64 + lane;        // n = item>>4, row = item&15
        int n = item >> 4, row = item & 15;
        int lo = 4 * n - 1; if (lo < 0) lo = 0;
        int hi = 4 * n + 3; if (hi > NC - 1) hi = NC - 1;
        float s = 0.f;
        for (int c = lo; c <= hi; ++c) s += Pw[swP(row, c)];
        pslw[n * 16 + row] = s;
    }
    wave_lds_fence();

    // ---- top-16 per row (lane = row; register-cached scan; ties -> lowest index) ----
    unsigned mymask = 0u;
    {
        float pv[32];
#pragma unroll
        for (int n = 0; n < 32; ++n) pv[n] = (lane < 16) ? pslw[n * 16 + lane] : 0.f;
        for (int it = 0; it < TOPN; ++it) {
            float best = -1.f; int bi = 0;
#pragma unroll
            for (int n = 0; n < 32; ++n) {
                float val = ((mymask >> n) & 1u) ? -2.f : pv[n];
                if (val > best) { best = val; bi = n; }
            }
            mymask |= 1u << bi;
        }
        mymask |= 1u << tile;              // own block
        if (lane >= 16) mymask = 0u;
    }
    unsigned um = mymask;
#pragma unroll
    for (int off = 32; off >= 1; off >>= 1) um |= __shfl_xor(um, off, 64);
    unsigned selreg[4];
#pragma unroll
    for (int r = 0; r < 4; ++r) selreg[r] = __shfl(mymask, 4 * g + r, 64);

    // ---- o_cmp = P · Vc (A from Pw f32 -> bf16, B from VcT global) ----
    f32x4 oc[4];
#pragma unroll
    for (int dt = 0; dt < 4; ++dt) { f32x4 z = {0.f, 0.f, 0.f, 0.f}; oc[dt] = z; }
#pragma unroll
    for (int kk = 0; kk < 4; ++kk) {
        float4 a0 = *(const float4*)&Pw[swP(lr, kk * 32 + g * 8)];
        float4 a1 = *(const float4*)&Pw[swP(lr, kk * 32 + g * 8 + 4)];
        s16x8 pa = pack8(a0, a1);
#pragma unroll
        for (int dt = 0; dt < 4; ++dt)
            oc[dt] = mfma16(pa, *(const s16x8*)(VcT + ((size_t)h * 64 + 16 * dt + lr) * 128 + kk * 32 + g * 8), oc[dt]);
    }

    // ================= branches 2+3: shared QK^T per K-block, no barriers =================
    const int winlo = (tile >= 8) ? (tile - 8) : 0;

    float m2[4], l2[4], m3[4], l3[4];
    f32x4 o2[4], o3[4];
#pragma unroll
    for (int r = 0; r < 4; ++r) { m2[r] = -1e30f; l2[r] = 0.f; m3[r] = -1e30f; l3[r] = 0.f; }
#pragma unroll
    for (int dt = 0; dt < 4; ++dt) { f32x4 z = {0.f, 0.f, 0.f, 0.f}; o2[dt] = z; o3[dt] = z; }

    for (int n = 0; n <= tile; ++n) {
        const bool sel_on = (um >> n) & 1u;
        const bool win_on = n >= winlo;
        if (!sel_on && !win_on) continue;
        const int base = n << 6;

        // QK^T from global bf16 K
        f32x4 s4[4];
#pragma unroll
        for (int ct = 0; ct < 4; ++ct) {
            f32x4 acc = {0.f, 0.f, 0.f, 0.f};
#pragma unroll
            for (int kk = 0; kk < 2; ++kk)
                acc = mfma16(qa[kk],
                    *(const s16x8*)(Kb + ((size_t)h * 2048 + base + 16 * ct + lr) * 64 + kk * 32 + g * 8), acc);
            s4[ct] = acc;
        }

        if (sel_on) {
            float rm[4] = {-3e38f, -3e38f, -3e38f, -3e38f};
#pragma unroll
            for (int ct = 0; ct < 4; ++ct)
#pragma unroll
                for (int r = 0; r < 4; ++r) {
                    int j = base + 16 * ct + lr;
                    bool ok = ((selreg[r] >> n) & 1u) && (j <= trow[r]);
                    float s = s4[ct][r] * SCALE;
                    if (ok) rm[r] = fmaxf(rm[r], s);
                }
#pragma unroll
            for (int off = 8; off >= 1; off >>= 1)
#pragma unroll
                for (int r = 0; r < 4; ++r) rm[r] = fmaxf(rm[r], __shfl_xor(rm[r], off, 64));
            float al[4], rs[4] = {0.f, 0.f, 0.f, 0.f};
#pragma unroll
            for (int r = 0; r < 4; ++r) {
                float mn = fmaxf(m2[r], rm[r]);
                al[r] = __expf(m2[r] - mn);
                m2[r] = mn;
            }
#pragma unroll
            for (int ct = 0; ct < 4; ++ct)
#pragma unroll
                for (int r = 0; r < 4; ++r) {
                    int j = base + 16 * ct + lr;
                    bool ok = ((selreg[r] >> n) & 1u) && (j <= trow[r]);
                    float p = ok ? __expf(s4[ct][r] * SCALE - m2[r]) : 0.f;
                    rs[r] += p;
                    Pb[swB(4 * g + r, 16 * ct + lr)] = f2b(p);
                }
#pragma unroll
            for (int off = 8; off >= 1; off >>= 1)
#pragma unroll
                for (int r = 0; r < 4; ++r) rs[r] += __shfl_xor(rs[r], off, 64);
#pragma unroll
            for (int r = 0; r < 4; ++r) l2[r] = l2[r] * al[r] + rs[r];
#pragma unroll
            for (int dt = 0; dt < 4; ++dt)
#pragma unroll
                for (int r = 0; r < 4; ++r) o2[dt][r] *= al[r];
        }
        if (win_on) {
            float rm[4] = {-3e38f, -3e38f, -3e38f, -3e38f};
#pragma unroll
            for (int ct = 0; ct < 4; ++ct)
#pragma unroll
                for (int r = 0; r < 4; ++r) {
                    int j = base + 16 * ct + lr;
                    bool ok = (j >= trow[r] - 511) && (j <= trow[r]);
                    float s = s4[ct][r] * SCALE;
                    if (ok) rm[r] = fmaxf(rm[r], s);
                }
#pragma unroll
            for (int off = 8; off >= 1; off >>= 1)
#pragma unroll
                for (int r = 0; r < 4; ++r) rm[r] = fmaxf(rm[r], __shfl_xor(rm[r], off, 64));
            float al[4], rs[4] = {0.f, 0.f, 0.f, 0.f};
#pragma unroll
            for (int r = 0; r < 4; ++r) {
                float mn = fmaxf(m3[r], rm[r]);
                al[r] = __expf(m3[r] - mn);
                m3[r] = mn;
            }
#pragma unroll
            for (int ct = 0; ct < 4; ++ct)
#pragma unroll
                for (int r = 0; r < 4; ++r) {
                    int j = base + 16 * ct + lr;
                    bool ok = (j >= trow[r] - 511) && (j <= trow[r]);
                    float p = ok ? __expf(s4[ct][r] * SCALE - m3[r]) : 0.f;
                    rs[r] += p;
                    Pb[2048 + swB(4 * g + r, 16 * ct + lr)] = f2b(p);
                }
#pragma unroll
            for (int off = 8; off >= 1; off >>= 1)
#pragma unroll
                for (int r = 0; r < 4; ++r) rs[r] += __shfl_xor(rs[r], off, 64);
#pragma unroll
            for (int r = 0; r < 4; ++r) l3[r] = l3[r] * al[r] + rs[r];
#pragma unroll
            for (int dt = 0; dt < 4; ++dt)
#pragma unroll
                for (int r = 0; r < 4; ++r) o3[dt][r] *= al[r];
        }
        wave_lds_fence();   // in-wave: P writes -> P reads

        if (sel_on) {
#pragma unroll
            for (int kk = 0; kk < 2; ++kk) {
                s16x8 pa = *(const s16x8*)&Pb[swB(lr, kk * 32 + g * 8)];
#pragma unroll
                for (int dt = 0; dt < 4; ++dt)
                    o2[dt] = mfma16(pa,
                        *(const s16x8*)(VtB + ((size_t)h * 64 + 16 * dt + lr) * 2048 + base + kk * 32 + g * 8), o2[dt]);
            }
        }
        if (win_on) {
#pragma unroll
            for (int kk = 0; kk < 2; ++kk) {
                s16x8 pa = *(const s16x8*)&Pb[2048 + swB(lr, kk * 32 + g * 8)];
#pragma unroll
                for (int dt = 0; dt < 4; ++dt)
                    o3[dt] = mfma16(pa,
                        *(const s16x8*)(VtB + ((size_t)h * 64 + 16 * dt + lr) * 2048 + base + kk * 32 + g * 8), o3[dt]);
            }
        }
        // next iteration's P writes are same-wave DS ops issued after these reads -> in-order, no WAR hazard
    }

    // ================= gated combine =================
#pragma unroll
    for (int r = 0; r < 4; ++r) {
        const float* gp = gat + (size_t)trow[r] * 3;
        float g0 = gp[0], g1 = gp[1], g2 = gp[2];
        float invc = nv[r] ? (1.f / l1[r]) : 0.f;
        float i2 = 1.f / l2[r], i3 = 1.f / l3[r];
#pragma unroll
        for (int dt = 0; dt < 4; ++dt) {
            float val = g0 * (oc[dt][r] * invc) + g1 * (o2[dt][r] * i2) + g2 * (o3[dt][r] * i3);
            out[((size_t)trow[r] * H_NUM + h) * D_DIM + 16 * dt + lr] = val;
        }
    }
}

extern "C" void kernel_launch(void* const* d_in, const int* in_sizes, int n_in,
                              void* d_out, int out_size, void* d_ws, size_t ws_size,
                              hipStream_t stream) {
    const float* q  = (const float*)d_in[0];
    const float* k  = (const float*)d_in[1];
    const float* v  = (const float*)d_in[2];
    const float* x  = (const float*)d_in[3];
    const float* Wg = (const float*)d_in[4];
    const float* bg = (const float*)d_in[5];
    float* out = (float*)d_out;

    // workspace layout
    ushort_t* Kb   = (ushort_t*)d_ws;                       // 16*2048*64
    ushort_t* VtB  = Kb  + (size_t)16 * 2048 * 64;          // 16*64*2048
    ushort_t* KcHi = VtB + (size_t)16 * 64 * 2048;          // 16*128*64
    ushort_t* KcLo = KcHi + (size_t)16 * 128 * 64;
    ushort_t* VcT  = KcLo + (size_t)16 * 128 * 64;          // 16*64*128
    float*    g    = (float*)(VcT + (size_t)16 * 64 * 128); // 2048*3

    nsa_compress<<<16 * 128, 64, 0, stream>>>(k, v, KcHi, KcLo, VcT);
    nsa_cast_k  <<<2048, 256, 0, stream>>>(k, Kb);
    nsa_cast_vt <<<256, 256, 0, stream>>>(v, VtB);
    nsa_gate    <<<S_LEN, 64, 0, stream>>>(x, Wg, bg, g);
    nsa_main    <<<512, 256, 0, stream>>>(q, Kb, VtB, KcHi, KcLo, VcT, g, out);
}